// Round 6
// baseline (436.948 us; speedup 1.0000x reference)
//
#include <hip/hip_runtime.h>

typedef unsigned short u16;
typedef unsigned int   uint;
typedef __attribute__((ext_vector_type(8))) short bf16x8;
typedef __attribute__((ext_vector_type(4))) float f32x4;

constexpr int NELEM = 100;
constexpr int EMBED = 256;
constexpr int HID   = 512;
constexpr int KX    = 306;     // EMBED + 50
constexpr int G     = 50;
constexpr int M     = 64;      // edges per block
constexpr int THREADS = 512;   // 8 waves
constexpr int HSTR  = 520;     // hbuf row stride (bf16 elems)

// frag-ready weight buffers in d_ws (bf16):
//  Wb : [10 ks][32 nt][64 lane][8]   (k==306 row carries b_in; >306 zero)
//  Gb : [ 2 ks][32 nt][64 lane][8]   (g>=50 zero)
//  Ob : [16 ks][64 lane][8]
//  Eb : emb_table converted to bf16 (optional, if ws fits)
constexpr int WB_ELEMS = 10 * 32 * 64 * 8;
constexpr int GB_ELEMS = 2 * 32 * 64 * 8;
constexpr int OB_ELEMS = 16 * 64 * 8;

__device__ __forceinline__ u16 f2bf(float x) {
    uint u = __float_as_uint(x);
    u = (u + 0x7fffu + ((u >> 16) & 1u)) >> 16;
    return (u16)u;
}
__device__ __forceinline__ uint pk2(float a, float b) {
    return (uint)f2bf(a) | ((uint)f2bf(b) << 16);
}
__device__ __forceinline__ float bflo(uint u) { return __uint_as_float(u << 16); }
__device__ __forceinline__ float bfhi(uint u) { return __uint_as_float(u & 0xffff0000u); }
__device__ __forceinline__ f32x4 mfma16(bf16x8 a, bf16x8 b, f32x4 c) {
    return __builtin_amdgcn_mfma_f32_16x16x32_bf16(a, b, c, 0, 0, 0);
}

// ---- prep: weights -> fragment-ready bf16 layouts --------------------------
__global__ void prep_kernel(const float* __restrict__ W_in,   // [512][306]
                            const float* __restrict__ gate_W, // [512][50]
                            const float* __restrict__ W_out,  // [8][512]
                            const float* __restrict__ b_in,   // [512]
                            u16* __restrict__ Wb,
                            u16* __restrict__ Gb,
                            u16* __restrict__ Ob) {
    int idx = blockIdx.x * 256 + threadIdx.x;
    if (idx < WB_ELEMS) {
        int j = idx & 7, lane = (idx >> 3) & 63, nt = (idx >> 9) & 31, ks = idx >> 14;
        int h = nt * 16 + (lane & 15);
        int k = ks * 32 + (lane >> 4) * 8 + j;
        float v = (k < KX) ? W_in[h * KX + k] : ((k == KX) ? b_in[h] : 0.f);
        Wb[idx] = f2bf(v);
    } else if (idx < WB_ELEMS + GB_ELEMS) {
        int i2 = idx - WB_ELEMS;
        int j = i2 & 7, lane = (i2 >> 3) & 63, nt = (i2 >> 9) & 31, ks = i2 >> 14;
        int h = nt * 16 + (lane & 15);
        int g = ks * 32 + (lane >> 4) * 8 + j;
        Gb[i2] = f2bf((g < G) ? gate_W[h * G + g] : 0.f);
    } else if (idx < WB_ELEMS + GB_ELEMS + OB_ELEMS) {
        int i2 = idx - WB_ELEMS - GB_ELEMS;
        int j = i2 & 7, lane = (i2 >> 3) & 63, ks = i2 >> 9;
        int n = lane & 15;
        int k = ks * 32 + (lane >> 4) * 8 + j;
        Ob[i2] = f2bf((n < 8) ? W_out[n * HID + k] : 0.f);
    }
}

// ---- prep: emb_table f32 -> bf16 ------------------------------------------
__global__ void conv_table_kernel(const float* __restrict__ src,
                                  uint* __restrict__ dst, int npairs) {
    int i = blockIdx.x * 256 + threadIdx.x;
    if (i < npairs) {
        float2 v = ((const float2*)src)[i];
        dst[i] = pk2(v.x, v.y);
    }
}

// ---- fused main kernel -----------------------------------------------------
template <bool BF16_TABLE>
__global__ __launch_bounds__(THREADS, 4)
void pair_embed_kernel(const int* __restrict__ anum,
                       const int* __restrict__ edge_index,
                       const int* __restrict__ edge_to_src,
                       const float* __restrict__ dist,
                       const float* __restrict__ emb_table,
                       const u16* __restrict__ Eb,
                       const float* __restrict__ b_out,
                       const u16* __restrict__ Wb,
                       const u16* __restrict__ Gb,
                       const u16* __restrict__ Ob,
                       float* __restrict__ out,
                       int E) {
    // union: afrag [10 ks][4 mt][64 lane][8] = 40 KB during GEMM,
    // then hbuf [64 m][520] bf16 = 66.5 KB for the out-projection.
    __shared__ __align__(16) u16 smem[M * HSTR];
    __shared__ int   rowbase[M];
    __shared__ float dste[M];
    u16* afrag = smem;
    u16* hbuf  = smem;

    const int t  = threadIdx.x;
    const int e0 = blockIdx.x * M;

    if (t < M) {
        int eg = e0 + t;
        int pair = 0; float d = 0.f;
        if (eg < E) {
            int src = edge_to_src[eg];
            pair = anum[edge_index[src]] + NELEM * anum[edge_index[E + src]];
            d = dist[eg];
        }
        rowbase[t] = pair * EMBED;
        dste[t]    = d;
    }
    __syncthreads();

    // ---- stage A-tile: 2560 16B chunks (wave-uniform ks/mt branch) --------
    {
        const float sp    = 12.0f / 49.0f;
        const float coeff = -0.5f / (sp * sp);
        #pragma unroll 1
        for (int p = 0; p < 5; ++p) {
            int cix   = p * THREADS + t;     // 0..2559
            int slot  = cix & 63;
            int km    = cix >> 6;            // 0..39
            int ks    = km >> 2, mt = km & 3;
            int m_low = slot >> 2, sub = slot & 3;
            int m     = mt * 16 + m_low;
            uint4 w;
            if (ks < 8) {
                if (BF16_TABLE) {
                    w = *(const uint4*)(Eb + rowbase[m] + ks * 32 + sub * 8);
                } else {
                    const float4* src = (const float4*)(emb_table + rowbase[m] + ks * 32 + sub * 8);
                    float4 v0 = src[0], v1 = src[1];
                    w.x = pk2(v0.x, v0.y); w.y = pk2(v0.z, v0.w);
                    w.z = pk2(v1.x, v1.y); w.w = pk2(v1.z, v1.w);
                }
            } else {
                int g0 = (ks - 8) * 32 + sub * 8;
                float d = dste[m];
                float f[8];
                #pragma unroll
                for (int j = 0; j < 8; ++j) {
                    int g = g0 + j;
                    float dd = d - sp * (float)g;
                    f[j] = (g < G) ? __expf(coeff * dd * dd) : ((g == G) ? 1.f : 0.f);
                }
                w.x = pk2(f[0], f[1]); w.y = pk2(f[2], f[3]);
                w.z = pk2(f[4], f[5]); w.w = pk2(f[6], f[7]);
            }
            *(uint4*)&afrag[((ks * 4 + mt) * 64 + sub * 16 + m_low) * 8] = w;
        }
    }
    __syncthreads();

    const int wave = t >> 6, lane = t & 63;
    const int col = lane & 15, quad = lane >> 4;
    const f32x4 z4 = {0.f, 0.f, 0.f, 0.f};

    uint hpack[2][2][4][2];   // [half][ntl][mt][pair] packed bf16 h values

    #pragma unroll
    for (int nh = 0; nh < 2; ++nh) {
        // ---- gate GEMM first (ks 8..9), then pack to bf16 (32 -> 16 regs) --
        uint gp[2][4][2];
        {
            f32x4 gacc[2][4];
            #pragma unroll
            for (int ntl = 0; ntl < 2; ++ntl)
                #pragma unroll
                for (int mt = 0; mt < 4; ++mt) gacc[ntl][mt] = z4;
            #pragma unroll
            for (int ks = 0; ks < 2; ++ks) {
                bf16x8 a[4];
                #pragma unroll
                for (int mt = 0; mt < 4; ++mt)
                    a[mt] = *(const bf16x8*)&afrag[(((8 + ks) * 4 + mt) * 64 + lane) * 8];
                #pragma unroll
                for (int ntl = 0; ntl < 2; ++ntl) {
                    int ntg = wave * 4 + nh * 2 + ntl;
                    bf16x8 b = *(const bf16x8*)&Gb[((ks * 32 + ntg) * 64 + lane) * 8];
                    #pragma unroll
                    for (int mt = 0; mt < 4; ++mt)
                        gacc[ntl][mt] = mfma16(a[mt], b, gacc[ntl][mt]);
                }
            }
            #pragma unroll
            for (int ntl = 0; ntl < 2; ++ntl)
                #pragma unroll
                for (int mt = 0; mt < 4; ++mt) {
                    gp[ntl][mt][0] = pk2(gacc[ntl][mt][0], gacc[ntl][mt][1]);
                    gp[ntl][mt][1] = pk2(gacc[ntl][mt][2], gacc[ntl][mt][3]);
                }
        }

        // ---- main GEMM (ks 0..9, bias folded at k=306) ---------------------
        f32x4 acc[2][4];
        #pragma unroll
        for (int ntl = 0; ntl < 2; ++ntl)
            #pragma unroll
            for (int mt = 0; mt < 4; ++mt) acc[ntl][mt] = z4;
        #pragma unroll 2
        for (int ks = 0; ks < 10; ++ks) {
            bf16x8 a[4];
            #pragma unroll
            for (int mt = 0; mt < 4; ++mt)
                a[mt] = *(const bf16x8*)&afrag[((ks * 4 + mt) * 64 + lane) * 8];
            #pragma unroll
            for (int ntl = 0; ntl < 2; ++ntl) {
                int ntg = wave * 4 + nh * 2 + ntl;
                bf16x8 b = *(const bf16x8*)&Wb[((ks * 32 + ntg) * 64 + lane) * 8];
                #pragma unroll
                for (int mt = 0; mt < 4; ++mt)
                    acc[ntl][mt] = mfma16(a[mt], b, acc[ntl][mt]);
            }
        }

        // ---- h = silu(pre) * gate -> packed regs (afrag still live) --------
        #pragma unroll
        for (int ntl = 0; ntl < 2; ++ntl) {
            #pragma unroll
            for (int mt = 0; mt < 4; ++mt) {
                float hv[4];
                #pragma unroll
                for (int r = 0; r < 4; ++r) {
                    float pre = acc[ntl][mt][r];
                    float s = pre / (1.f + __expf(-pre));
                    float g = (r == 0) ? bflo(gp[ntl][mt][0])
                            : (r == 1) ? bfhi(gp[ntl][mt][0])
                            : (r == 2) ? bflo(gp[ntl][mt][1])
                                       : bfhi(gp[ntl][mt][1]);
                    hv[r] = s * g;
                }
                hpack[nh][ntl][mt][0] = pk2(hv[0], hv[1]);
                hpack[nh][ntl][mt][1] = pk2(hv[2], hv[3]);
            }
        }
    }
    __syncthreads();   // all afrag reads complete; smem becomes hbuf

    // ---- spill h registers -> hbuf[m][hg] ---------------------------------
    #pragma unroll
    for (int nh = 0; nh < 2; ++nh) {
        #pragma unroll
        for (int ntl = 0; ntl < 2; ++ntl) {
            int hg = wave * 64 + (nh * 2 + ntl) * 16 + col;
            #pragma unroll
            for (int mt = 0; mt < 4; ++mt) {
                int m0 = mt * 16 + quad * 4;
                uint p0 = hpack[nh][ntl][mt][0], p1 = hpack[nh][ntl][mt][1];
                hbuf[(m0 + 0) * HSTR + hg] = (u16)p0;
                hbuf[(m0 + 1) * HSTR + hg] = (u16)(p0 >> 16);
                hbuf[(m0 + 2) * HSTR + hg] = (u16)p1;
                hbuf[(m0 + 3) * HSTR + hg] = (u16)(p1 >> 16);
            }
        }
    }
    __syncthreads();

    // ---- out-proj: wave w handles m-tile w (full K=512), direct store -----
    if (wave < 4) {
        const int mt = wave;
        f32x4 oacc = z4;
        #pragma unroll 4
        for (int ks = 0; ks < 16; ++ks) {
            bf16x8 a = *(const bf16x8*)&hbuf[(mt * 16 + col) * HSTR + ks * 32 + quad * 8];
            bf16x8 b = *(const bf16x8*)&Ob[(ks * 64 + lane) * 8];
            oacc = mfma16(a, b, oacc);
        }
        if (col < 8) {
            int eg0 = e0 + mt * 16 + quad * 4;
            float bo = b_out[col];
            if (eg0 + 3 < E) {
                float4 v = make_float4(oacc[0] + bo, oacc[1] + bo,
                                       oacc[2] + bo, oacc[3] + bo);
                *(float4*)&out[col * E + eg0] = v;
            } else {
                #pragma unroll
                for (int r = 0; r < 4; ++r)
                    if (eg0 + r < E) out[col * E + eg0 + r] = oacc[r] + bo;
            }
        }
    }
}

extern "C" void kernel_launch(void* const* d_in, const int* in_sizes, int n_in,
                              void* d_out, int out_size, void* d_ws, size_t ws_size,
                              hipStream_t stream) {
    const int*   anum        = (const int*)d_in[0];
    const int*   edge_index  = (const int*)d_in[1];
    const int*   edge_to_src = (const int*)d_in[2];
    const float* dist        = (const float*)d_in[3];
    const float* emb_table   = (const float*)d_in[4];
    const float* gate_W      = (const float*)d_in[5];
    const float* W_in        = (const float*)d_in[6];
    const float* b_in        = (const float*)d_in[7];
    const float* W_out       = (const float*)d_in[8];
    const float* b_out       = (const float*)d_in[9];
    const int E       = in_sizes[3];
    const int TBL     = in_sizes[4];           // NELEM^2 * EMBED elements

    u16* Wb = (u16*)d_ws;
    u16* Gb = Wb + WB_ELEMS;
    u16* Ob = Gb + GB_ELEMS;
    u16* Eb = Ob + OB_ELEMS;

    const size_t need_bf16 = (size_t)(WB_ELEMS + GB_ELEMS + OB_ELEMS + TBL) * sizeof(u16);
    const bool use_bf16_table = ws_size >= need_bf16;

    int total = WB_ELEMS + GB_ELEMS + OB_ELEMS;
    prep_kernel<<<(total + 255) / 256, 256, 0, stream>>>(
        W_in, gate_W, W_out, b_in, Wb, Gb, Ob);

    const int nblocks = (E + M - 1) / M;
    if (use_bf16_table) {
        int npairs = TBL / 2;
        conv_table_kernel<<<(npairs + 255) / 256, 256, 0, stream>>>(
            emb_table, (uint*)Eb, npairs);
        pair_embed_kernel<true><<<nblocks, THREADS, 0, stream>>>(
            anum, edge_index, edge_to_src, dist, emb_table, Eb,
            b_out, Wb, Gb, Ob, (float*)d_out, E);
    } else {
        pair_embed_kernel<false><<<nblocks, THREADS, 0, stream>>>(
            anum, edge_index, edge_to_src, dist, emb_table, Eb,
            b_out, Wb, Gb, Ob, (float*)d_out, E);
    }
}

// Round 7
// 354.416 us; speedup vs baseline: 1.2329x; 1.2329x over previous
//
#include <hip/hip_runtime.h>

typedef unsigned short u16;
typedef unsigned int   uint;
typedef __attribute__((ext_vector_type(8))) short bf16x8;
typedef __attribute__((ext_vector_type(4))) float f32x4;

constexpr int NELEM = 100;
constexpr int EMBED = 256;
constexpr int HID   = 512;
constexpr int KX    = 306;     // EMBED + 50
constexpr int G     = 50;
constexpr int M     = 64;      // edges per block
constexpr int THREADS = 512;   // 8 waves
constexpr int HSTR  = 520;     // hbuf row stride (bf16 elems)

// frag-ready weight buffers in d_ws (bf16):
//  Wb : [10 ks][32 nt][64 lane][8]   (k==306 row carries b_in; >306 zero)
//  Gb : [ 2 ks][32 nt][64 lane][8]   (g>=50 zero)
//  Ob : [16 ks][64 lane][8]
//  Eb : emb_table converted to bf16 (optional, if ws fits)
constexpr int WB_ELEMS = 10 * 32 * 64 * 8;
constexpr int GB_ELEMS = 2 * 32 * 64 * 8;
constexpr int OB_ELEMS = 16 * 64 * 8;

__device__ __forceinline__ u16 f2bf(float x) {
    uint u = __float_as_uint(x);
    u = (u + 0x7fffu + ((u >> 16) & 1u)) >> 16;
    return (u16)u;
}
__device__ __forceinline__ uint pk2(float a, float b) {
    return (uint)f2bf(a) | ((uint)f2bf(b) << 16);
}
__device__ __forceinline__ f32x4 mfma16(bf16x8 a, bf16x8 b, f32x4 c) {
    return __builtin_amdgcn_mfma_f32_16x16x32_bf16(a, b, c, 0, 0, 0);
}

// ---- prep: weights -> fragment-ready bf16 layouts --------------------------
__global__ void prep_kernel(const float* __restrict__ W_in,   // [512][306]
                            const float* __restrict__ gate_W, // [512][50]
                            const float* __restrict__ W_out,  // [8][512]
                            const float* __restrict__ b_in,   // [512]
                            u16* __restrict__ Wb,
                            u16* __restrict__ Gb,
                            u16* __restrict__ Ob) {
    int idx = blockIdx.x * 256 + threadIdx.x;
    if (idx < WB_ELEMS) {
        int j = idx & 7, lane = (idx >> 3) & 63, nt = (idx >> 9) & 31, ks = idx >> 14;
        int h = nt * 16 + (lane & 15);
        int k = ks * 32 + (lane >> 4) * 8 + j;
        float v = (k < KX) ? W_in[h * KX + k] : ((k == KX) ? b_in[h] : 0.f);
        Wb[idx] = f2bf(v);
    } else if (idx < WB_ELEMS + GB_ELEMS) {
        int i2 = idx - WB_ELEMS;
        int j = i2 & 7, lane = (i2 >> 3) & 63, nt = (i2 >> 9) & 31, ks = i2 >> 14;
        int h = nt * 16 + (lane & 15);
        int g = ks * 32 + (lane >> 4) * 8 + j;
        Gb[i2] = f2bf((g < G) ? gate_W[h * G + g] : 0.f);
    } else if (idx < WB_ELEMS + GB_ELEMS + OB_ELEMS) {
        int i2 = idx - WB_ELEMS - GB_ELEMS;
        int j = i2 & 7, lane = (i2 >> 3) & 63, ks = i2 >> 9;
        int n = lane & 15;
        int k = ks * 32 + (lane >> 4) * 8 + j;
        Ob[i2] = f2bf((n < 8) ? W_out[n * HID + k] : 0.f);
    }
}

// ---- prep: emb_table f32 -> bf16 ------------------------------------------
__global__ void conv_table_kernel(const float* __restrict__ src,
                                  uint* __restrict__ dst, int npairs) {
    int i = blockIdx.x * 256 + threadIdx.x;
    if (i < npairs) {
        float2 v = ((const float2*)src)[i];
        dst[i] = pk2(v.x, v.y);
    }
}

// ---- fused main kernel -----------------------------------------------------
template <bool BF16_TABLE>
__global__ __launch_bounds__(THREADS, 4)
void pair_embed_kernel(const int* __restrict__ anum,
                       const int* __restrict__ edge_index,
                       const int* __restrict__ edge_to_src,
                       const float* __restrict__ dist,
                       const float* __restrict__ emb_table,
                       const u16* __restrict__ Eb,
                       const float* __restrict__ b_out,
                       const u16* __restrict__ Wb,
                       const u16* __restrict__ Gb,
                       const u16* __restrict__ Ob,
                       float* __restrict__ out,
                       int E) {
    // union: afrag [10 ks][4 mt][64 lane][8] = 40 KB during GEMM,
    // then hbuf [64 e][520] bf16 = 66.5 KB for the out-projection.
    __shared__ __align__(16) u16 smem[M * HSTR];
    __shared__ float red[8][64][4];     // out-proj partials (k-split)
    __shared__ int   rowbase[M];
    __shared__ float dste[M];
    u16* afrag = smem;
    u16* hbuf  = smem;

    const int t  = threadIdx.x;
    const int e0 = blockIdx.x * M;

    if (t < M) {
        int eg = e0 + t;
        int pair = 0; float d = 0.f;
        if (eg < E) {
            int src = edge_to_src[eg];
            pair = anum[edge_index[src]] + NELEM * anum[edge_index[E + src]];
            d = dist[eg];
        }
        rowbase[t] = pair * EMBED;
        dste[t]    = d;
    }
    __syncthreads();

    // ---- stage A-tile: 2560 16B chunks (wave-uniform ks/mt branch) --------
    {
        const float sp    = 12.0f / 49.0f;
        const float coeff = -0.5f / (sp * sp);
        #pragma unroll 1
        for (int p = 0; p < 5; ++p) {
            int cix   = p * THREADS + t;     // 0..2559
            int slot  = cix & 63;
            int km    = cix >> 6;            // 0..39
            int ks    = km >> 2, mt = km & 3;
            int m_low = slot >> 2, sub = slot & 3;
            int m     = mt * 16 + m_low;
            uint4 w;
            if (ks < 8) {
                if (BF16_TABLE) {
                    w = *(const uint4*)(Eb + rowbase[m] + ks * 32 + sub * 8);
                } else {
                    const float4* src = (const float4*)(emb_table + rowbase[m] + ks * 32 + sub * 8);
                    float4 v0 = src[0], v1 = src[1];
                    w.x = pk2(v0.x, v0.y); w.y = pk2(v0.z, v0.w);
                    w.z = pk2(v1.x, v1.y); w.w = pk2(v1.z, v1.w);
                }
            } else {
                int g0 = (ks - 8) * 32 + sub * 8;
                float d = dste[m];
                float f[8];
                #pragma unroll
                for (int j = 0; j < 8; ++j) {
                    int g = g0 + j;
                    float dd = d - sp * (float)g;
                    f[j] = (g < G) ? __expf(coeff * dd * dd) : ((g == G) ? 1.f : 0.f);
                }
                w.x = pk2(f[0], f[1]); w.y = pk2(f[2], f[3]);
                w.z = pk2(f[4], f[5]); w.w = pk2(f[6], f[7]);
            }
            *(uint4*)&afrag[((ks * 4 + mt) * 64 + sub * 16 + m_low) * 8] = w;
        }
    }
    __syncthreads();

    const int wave = t >> 6, lane = t & 63;
    const int col = lane & 15, quad = lane >> 4;
    const f32x4 z4 = {0.f, 0.f, 0.f, 0.f};

    // hpack[nh][ntl][mt][2]: h for 4 consecutive hidden (rows) of edge `col`
    uint hpack[2][2][4][2];

    #pragma unroll
    for (int nh = 0; nh < 2; ++nh) {
        // ---- main GEMM (A = Wb, B = x-frags): D[h][e] ----------------------
        f32x4 acc[2][4];
        #pragma unroll
        for (int ntl = 0; ntl < 2; ++ntl)
            #pragma unroll
            for (int mt = 0; mt < 4; ++mt) acc[ntl][mt] = z4;
        #pragma unroll 2
        for (int ks = 0; ks < 10; ++ks) {
            bf16x8 a[4];
            #pragma unroll
            for (int mt = 0; mt < 4; ++mt)
                a[mt] = *(const bf16x8*)&afrag[((ks * 4 + mt) * 64 + lane) * 8];
            #pragma unroll
            for (int ntl = 0; ntl < 2; ++ntl) {
                int ntg = wave * 4 + nh * 2 + ntl;
                bf16x8 w = *(const bf16x8*)&Wb[((ks * 32 + ntg) * 64 + lane) * 8];
                #pragma unroll
                for (int mt = 0; mt < 4; ++mt)
                    acc[ntl][mt] = mfma16(w, a[mt], acc[ntl][mt]);   // A=W, B=x
            }
        }

        // ---- gate GEMM after main: gacc coexists with acc in AGPR ----------
        f32x4 gacc[2][4];
        #pragma unroll
        for (int ntl = 0; ntl < 2; ++ntl)
            #pragma unroll
            for (int mt = 0; mt < 4; ++mt) gacc[ntl][mt] = z4;
        #pragma unroll
        for (int ks = 0; ks < 2; ++ks) {
            bf16x8 a[4];
            #pragma unroll
            for (int mt = 0; mt < 4; ++mt)
                a[mt] = *(const bf16x8*)&afrag[(((8 + ks) * 4 + mt) * 64 + lane) * 8];
            #pragma unroll
            for (int ntl = 0; ntl < 2; ++ntl) {
                int ntg = wave * 4 + nh * 2 + ntl;
                bf16x8 g = *(const bf16x8*)&Gb[((ks * 32 + ntg) * 64 + lane) * 8];
                #pragma unroll
                for (int mt = 0; mt < 4; ++mt)
                    gacc[ntl][mt] = mfma16(g, a[mt], gacc[ntl][mt]);
            }
        }

        // ---- h = silu(pre) * gate -> packed regs (fp32 gate, no rounding) --
        #pragma unroll
        for (int ntl = 0; ntl < 2; ++ntl) {
            #pragma unroll
            for (int mt = 0; mt < 4; ++mt) {
                float hv[4];
                #pragma unroll
                for (int r = 0; r < 4; ++r) {
                    float pre = acc[ntl][mt][r];
                    float s = pre / (1.f + __expf(-pre));
                    hv[r] = s * gacc[ntl][mt][r];
                }
                hpack[nh][ntl][mt][0] = pk2(hv[0], hv[1]);
                hpack[nh][ntl][mt][1] = pk2(hv[2], hv[3]);
            }
        }
    }
    __syncthreads();   // all afrag reads complete; smem becomes hbuf

    // ---- h-writes: 4 consecutive hidden per lane -> one b64 ---------------
    #pragma unroll
    for (int nh = 0; nh < 2; ++nh) {
        #pragma unroll
        for (int ntl = 0; ntl < 2; ++ntl) {
            int h0 = (wave * 4 + nh * 2 + ntl) * 16 + quad * 4;
            #pragma unroll
            for (int mt = 0; mt < 4; ++mt) {
                int e = mt * 16 + col;
                *(uint2*)&hbuf[e * HSTR + h0] =
                    make_uint2(hpack[nh][ntl][mt][0], hpack[nh][ntl][mt][1]);
            }
        }
    }
    __syncthreads();

    // ---- out-proj: 8-wave split (4 m-tiles x 2 k-halves) ------------------
    {
        const int mt = wave & 3, kh = wave >> 2;
        f32x4 oacc = z4;
        #pragma unroll
        for (int kk = 0; kk < 8; ++kk) {
            int ks = kh * 8 + kk;
            bf16x8 a = *(const bf16x8*)&hbuf[(mt * 16 + col) * HSTR + ks * 32 + quad * 8];
            bf16x8 b = *(const bf16x8*)&Ob[(ks * 64 + lane) * 8];
            oacc = mfma16(a, b, oacc);
        }
        *(float4*)&red[wave][lane][0] = *(float4*)&oacc;
    }
    __syncthreads();

    // ---- final reduce (k-halves) + write ----------------------------------
    if (t < 256) {
        const int mt = t >> 6, l = t & 63;
        const int c  = l & 15;
        float4 s;
        s.x = red[mt][l][0] + red[mt + 4][l][0];
        s.y = red[mt][l][1] + red[mt + 4][l][1];
        s.z = red[mt][l][2] + red[mt + 4][l][2];
        s.w = red[mt][l][3] + red[mt + 4][l][3];
        if (c < 8) {
            int eg0 = e0 + mt * 16 + (l >> 4) * 4;
            float bo = b_out[c];
            if (eg0 + 3 < E) {
                float4 v = make_float4(s.x + bo, s.y + bo, s.z + bo, s.w + bo);
                *(float4*)&out[c * E + eg0] = v;
            } else {
                float sv[4] = {s.x, s.y, s.z, s.w};
                #pragma unroll
                for (int r = 0; r < 4; ++r)
                    if (eg0 + r < E) out[c * E + eg0 + r] = sv[r] + bo;
            }
        }
    }
}

extern "C" void kernel_launch(void* const* d_in, const int* in_sizes, int n_in,
                              void* d_out, int out_size, void* d_ws, size_t ws_size,
                              hipStream_t stream) {
    const int*   anum        = (const int*)d_in[0];
    const int*   edge_index  = (const int*)d_in[1];
    const int*   edge_to_src = (const int*)d_in[2];
    const float* dist        = (const float*)d_in[3];
    const float* emb_table   = (const float*)d_in[4];
    const float* gate_W      = (const float*)d_in[5];
    const float* W_in        = (const float*)d_in[6];
    const float* b_in        = (const float*)d_in[7];
    const float* W_out       = (const float*)d_in[8];
    const float* b_out       = (const float*)d_in[9];
    const int E   = in_sizes[3];
    const int TBL = in_sizes[4];               // NELEM^2 * EMBED elements

    u16* Wb = (u16*)d_ws;
    u16* Gb = Wb + WB_ELEMS;
    u16* Ob = Gb + GB_ELEMS;
    u16* Eb = Ob + OB_ELEMS;

    const size_t need_bf16 = (size_t)(WB_ELEMS + GB_ELEMS + OB_ELEMS + TBL) * sizeof(u16);
    const bool use_bf16_table = ws_size >= need_bf16;

    int total = WB_ELEMS + GB_ELEMS + OB_ELEMS;
    prep_kernel<<<(total + 255) / 256, 256, 0, stream>>>(
        W_in, gate_W, W_out, b_in, Wb, Gb, Ob);

    const int nblocks = (E + M - 1) / M;
    if (use_bf16_table) {
        int npairs = TBL / 2;
        conv_table_kernel<<<(npairs + 255) / 256, 256, 0, stream>>>(
            emb_table, (uint*)Eb, npairs);
        pair_embed_kernel<true><<<nblocks, THREADS, 0, stream>>>(
            anum, edge_index, edge_to_src, dist, emb_table, Eb,
            b_out, Wb, Gb, Ob, (float*)d_out, E);
    } else {
        pair_embed_kernel<false><<<nblocks, THREADS, 0, stream>>>(
            anum, edge_index, edge_to_src, dist, emb_table, Eb,
            b_out, Wb, Gb, Ob, (float*)d_out, E);
    }
}